// Round 1
// baseline (887.946 us; speedup 1.0000x reference)
//
#include <hip/hip_runtime.h>
#include <hip/hip_bf16.h>
#include <stdint.h>

#define NN 10000
#define FF 128
#define EE 320000
#define TT (EE + NN)
#define EMD_ 128
#define NEG 0.2f

typedef __attribute__((ext_vector_type(8))) short bf16x8;
typedef __attribute__((ext_vector_type(4))) float f32x4;

struct Br {
  int* cnt;        // N (histogram, then cursor)
  int* rowptr;     // N+1
  int* srcidx;     // T
  float* alpha;    // T
  float* hp;       // N*F  (h' = h@W of current layer)
  float* s1;       // N
  float* s2;       // N
  float* H;        // 3*N*F (per-layer outputs, also next-layer input)
  uint16_t* xb;    // N*F bf16 (branch output, conv result)
  float* wct;      // 384*128 (transposed conv weight)
};

__device__ __forceinline__ uint16_t f2bf(float f) {
  uint32_t u = __float_as_uint(f);
  u += 0x7fff + ((u >> 16) & 1);
  return (uint16_t)(u >> 16);
}

__global__ void k_init(Br b0, Br b1) {
  Br& b = blockIdx.y ? b1 : b0;
  int i = blockIdx.x * 256 + threadIdx.x;
  if (i < NN) b.cnt[i] = 1;   // self loop
}

__global__ void k_hist(Br b0, Br b1, const int* em, const int* ed) {
  int br = blockIdx.y;
  Br& b = br ? b1 : b0;
  const int* dstp = (br ? ed : em) + EE;  // edges[1]
  int i = blockIdx.x * 256 + threadIdx.x;
  if (i < EE) atomicAdd(&b.cnt[dstp[i]], 1);
}

__global__ __launch_bounds__(1024) void k_scan(Br b0, Br b1) {
  Br& b = blockIdx.x ? b1 : b0;
  __shared__ int sh[2][1024];
  int t = threadIdx.x;
  int base = t * 10;
  int loc[10];
  int s = 0;
  for (int j = 0; j < 10; ++j) {
    int i = base + j;
    int c = (i < NN) ? b.cnt[i] : 0;
    loc[j] = s;
    s += c;
  }
  sh[0][t] = s;
  __syncthreads();
  int cur = 0;
  for (int off = 1; off < 1024; off <<= 1) {
    int v = sh[cur][t];
    if (t >= off) v += sh[cur][t - off];
    sh[cur ^ 1][t] = v;
    __syncthreads();
    cur ^= 1;
  }
  int excl = sh[cur][t] - s;
  for (int j = 0; j < 10; ++j) {
    int i = base + j;
    if (i < NN) {
      int v = excl + loc[j];
      b.rowptr[i] = v;
      b.cnt[i] = v;   // becomes cursor
    }
  }
  if (t == 0) b.rowptr[NN] = TT;
}

__global__ void k_scatter(Br b0, Br b1, const int* em, const int* ed) {
  int br = blockIdx.y;
  Br& b = br ? b1 : b0;
  const int* e = br ? ed : em;
  int i = blockIdx.x * 256 + threadIdx.x;
  if (i >= TT) return;
  int s, d;
  if (i < EE) { s = e[i]; d = e[EE + i]; }
  else { s = d = i - EE; }
  int pos = atomicAdd(&b.cnt[d], 1);
  b.srcidx[pos] = s;
}

__global__ void k_twc(Br b0, Br b1, const float* wcx, const float* wcy) {
  int br = blockIdx.y;
  Br& b = br ? b1 : b0;
  const float* wc = br ? wcy : wcx;
  int i = blockIdx.x * 256 + threadIdx.x;  // over 384*128, i = k*128+e
  if (i >= 384 * EMD_) return;
  int k = i >> 7, e2 = i & 127;
  b.wct[i] = wc[e2 * 384 + k];
}

// h' = in @ W  (64x64 tile per block, 4x4 micro-tile)
__global__ __launch_bounds__(256) void k_ngemm(Br b0, Br b1, const float* in0, const float* in1,
                                               const float* W0, const float* W1) {
  int br = blockIdx.z;
  Br& b = br ? b1 : b0;
  const float* in = br ? in1 : in0;
  const float* W = br ? W1 : W0;
  __shared__ float Alds[64][128];
  __shared__ float Wlds[128][64];
  int t = threadIdx.x;
  int r0 = blockIdx.x * 64;
  int c0 = blockIdx.y * 64;
  for (int p = 0; p < 8; ++p) {
    int idx = p * 256 + t;      // 2048 float4 = 64 rows x 32
    int r = idx >> 5, cq = idx & 31;
    int gr = r0 + r; if (gr > NN - 1) gr = NN - 1;
    ((float4*)&Alds[r][0])[cq] = ((const float4*)(in + (size_t)gr * FF))[cq];
  }
  for (int p = 0; p < 8; ++p) {
    int idx = p * 256 + t;      // 2048 float4 = 128 k x 16
    int k = idx >> 4, cq = idx & 15;
    ((float4*)&Wlds[k][0])[cq] = *(const float4*)(W + k * FF + c0 + cq * 4);
  }
  __syncthreads();
  int tx = t & 15, ty = t >> 4;
  float acc[4][4] = {};
  for (int k = 0; k < 128; ++k) {
    float bv[4];
    *(float4*)bv = *(float4*)&Wlds[k][tx * 4];
#pragma unroll
    for (int i = 0; i < 4; ++i) {
      float a = Alds[ty * 4 + i][k];
#pragma unroll
      for (int j = 0; j < 4; ++j) acc[i][j] += a * bv[j];
    }
  }
  for (int i = 0; i < 4; ++i) {
    int gr = r0 + ty * 4 + i;
    if (gr < NN) {
      float4 v = { acc[i][0], acc[i][1], acc[i][2], acc[i][3] };
      *(float4*)(b.hp + (size_t)gr * FF + c0 + tx * 4) = v;
    }
  }
}

// s1 = h' @ a_src, s2 = h' @ a_dst  (wave per row)
__global__ __launch_bounds__(256) void k_scores(Br b0, Br b1, const float* as0, const float* as1,
                                                const float* ad0, const float* ad1) {
  int br = blockIdx.y;
  Br& b = br ? b1 : b0;
  const float* asrc = br ? as1 : as0;
  const float* adst = br ? ad1 : ad0;
  int w = threadIdx.x >> 6, lane = threadIdx.x & 63;
  int r = blockIdx.x * 4 + w;
  if (r >= NN) return;
  const float* hr = b.hp + (size_t)r * FF;
  float v0 = hr[lane], v1 = hr[64 + lane];
  float s1v = v0 * asrc[lane] + v1 * asrc[64 + lane];
  float s2v = v0 * adst[lane] + v1 * adst[64 + lane];
  for (int off = 32; off; off >>= 1) {
    s1v += __shfl_xor(s1v, off);
    s2v += __shfl_xor(s2v, off);
  }
  if (lane == 0) { b.s1[r] = s1v; b.s2[r] = s2v; }
}

// segment softmax over dst (wave per node), writes per-edge alpha
__global__ __launch_bounds__(256) void k_softmax(Br b0, Br b1) {
  int br = blockIdx.y;
  Br& b = br ? b1 : b0;
  int w = threadIdx.x >> 6, lane = threadIdx.x & 63;
  int i = blockIdx.x * 4 + w;
  if (i >= NN) return;
  int beg = b.rowptr[i], end = b.rowptr[i + 1];
  float s2i = b.s2[i];
  float m = -1e30f;
  for (int j = beg + lane; j < end; j += 64) {
    float e = b.s1[b.srcidx[j]] + s2i;
    e = e >= 0.f ? e : NEG * e;
    m = fmaxf(m, e);
  }
  for (int off = 32; off; off >>= 1) m = fmaxf(m, __shfl_xor(m, off));
  float z = 0.f;
  for (int j = beg + lane; j < end; j += 64) {
    float e = b.s1[b.srcidx[j]] + s2i;
    e = e >= 0.f ? e : NEG * e;
    z += __expf(e - m);
  }
  for (int off = 32; off; off >>= 1) z += __shfl_xor(z, off);
  float rz = 1.0f / z;
  for (int j = beg + lane; j < end; j += 64) {
    float e = b.s1[b.srcidx[j]] + s2i;
    e = e >= 0.f ? e : NEG * e;
    b.alpha[j] = __expf(e - m) * rz;
  }
}

// out[i] = relu(sum_j alpha_j * h'[src_j] + bias), store into H[l]
__global__ __launch_bounds__(128) void k_agg(Br b0, Br b1, const float* bias0, const float* bias1, int lidx) {
  int br = blockIdx.y;
  Br& b = br ? b1 : b0;
  const float* bias = br ? bias1 : bias0;
  int i = blockIdx.x;
  int f = threadIdx.x;
  int beg = b.rowptr[i], end = b.rowptr[i + 1];
  float acc = 0.f;
  for (int j = beg; j < end; ++j) {
    int s = b.srcidx[j];
    acc += b.alpha[j] * b.hp[(size_t)s * FF + f];
  }
  acc += bias[f];
  acc = fmaxf(acc, 0.f);
  b.H[(size_t)lidx * NN * FF + (size_t)i * FF + f] = acc;
}

// out[n,e] = sum_{l,f} H[l,n,f]*Wc[e,l,f] + bc[e]  -> bf16
__global__ __launch_bounds__(256) void k_conv(Br b0, Br b1, const float* bc0, const float* bc1) {
  int br = blockIdx.z;
  Br& b = br ? b1 : b0;
  const float* bc = br ? bc1 : bc0;
  __shared__ float Alds[64][128];
  __shared__ float Wlds[128][64];
  int t = threadIdx.x;
  int r0 = blockIdx.x * 64, c0 = blockIdx.y * 64;
  int tx = t & 15, ty = t >> 4;
  float acc[4][4] = {};
  for (int l = 0; l < 3; ++l) {
    __syncthreads();
    const float* Hl = b.H + (size_t)l * NN * FF;
    for (int p = 0; p < 8; ++p) {
      int idx = p * 256 + t;
      int r = idx >> 5, cq = idx & 31;
      int gr = r0 + r; if (gr > NN - 1) gr = NN - 1;
      ((float4*)&Alds[r][0])[cq] = ((const float4*)(Hl + (size_t)gr * FF))[cq];
    }
    for (int p = 0; p < 8; ++p) {
      int idx = p * 256 + t;
      int k = idx >> 4, cq = idx & 15;
      ((float4*)&Wlds[k][0])[cq] = *(const float4*)(b.wct + (size_t)(l * FF + k) * EMD_ + c0 + cq * 4);
    }
    __syncthreads();
    for (int k = 0; k < 128; ++k) {
      float bv[4];
      *(float4*)bv = *(float4*)&Wlds[k][tx * 4];
#pragma unroll
      for (int i = 0; i < 4; ++i) {
        float a = Alds[ty * 4 + i][k];
#pragma unroll
        for (int j = 0; j < 4; ++j) acc[i][j] += a * bv[j];
      }
    }
  }
  for (int i = 0; i < 4; ++i) {
    int gr = r0 + ty * 4 + i;
    if (gr < NN) {
      for (int j = 0; j < 4; ++j) {
        int c = c0 + tx * 4 + j;
        b.xb[(size_t)gr * EMD_ + c] = f2bf(acc[i][j] + bc[c]);
      }
    }
  }
}

// C = X @ Y^T  (bf16 MFMA, 128x128 tile, K=128 single shot, XOR-swizzled LDS)
__global__ __launch_bounds__(256) void k_final(const uint16_t* xb, const uint16_t* yb, float* out) {
  __shared__ __align__(16) uint16_t Al[128 * 128];
  __shared__ __align__(16) uint16_t Bl[128 * 128];
  int t = threadIdx.x;
  int brow = blockIdx.x * 128, bcol = blockIdx.y * 128;
  for (int p = 0; p < 8; ++p) {
    int idx = p * 256 + t;           // 2048 = 128 rows x 16 slots (16B each)
    int row = idx >> 4, slot = idx & 15;
    int sl = slot ^ (row & 7);
    int ga = brow + row; if (ga > NN - 1) ga = NN - 1;
    int gb = bcol + row; if (gb > NN - 1) gb = NN - 1;
    ((int4*)(Al + row * 128))[sl] = ((const int4*)(xb + (size_t)ga * 128))[slot];
    ((int4*)(Bl + row * 128))[sl] = ((const int4*)(yb + (size_t)gb * 128))[slot];
  }
  __syncthreads();
  int w = t >> 6, lane = t & 63;
  int wr = (w >> 1) * 64, wc = (w & 1) * 64;
  int rrow = lane & 15, kgrp = lane >> 4;
  f32x4 acc[4][4];
#pragma unroll
  for (int m = 0; m < 4; ++m)
#pragma unroll
    for (int n = 0; n < 4; ++n) acc[m][n] = (f32x4){0.f, 0.f, 0.f, 0.f};
#pragma unroll
  for (int kc = 0; kc < 4; ++kc) {
    bf16x8 af[4], bfr[4];
#pragma unroll
    for (int m = 0; m < 4; ++m) {
      int row = wr + m * 16 + rrow;
      int slot = (kc * 4 + kgrp) ^ (row & 7);
      af[m] = *(const bf16x8*)(Al + row * 128 + slot * 8);
    }
#pragma unroll
    for (int n = 0; n < 4; ++n) {
      int row = wc + n * 16 + rrow;
      int slot = (kc * 4 + kgrp) ^ (row & 7);
      bfr[n] = *(const bf16x8*)(Bl + row * 128 + slot * 8);
    }
#pragma unroll
    for (int m = 0; m < 4; ++m)
#pragma unroll
      for (int n = 0; n < 4; ++n)
        acc[m][n] = __builtin_amdgcn_mfma_f32_16x16x32_bf16(af[m], bfr[n], acc[m][n], 0, 0, 0);
  }
  int crow0 = brow + wr + kgrp * 4;
  int ccol0 = bcol + wc + rrow;
#pragma unroll
  for (int m = 0; m < 4; ++m) {
#pragma unroll
    for (int n = 0; n < 4; ++n) {
      int col = ccol0 + n * 16;
      if (col < NN) {
#pragma unroll
        for (int r = 0; r < 4; ++r) {
          int row = crow0 + m * 16 + r;
          if (row < NN) out[(size_t)row * NN + col] = acc[m][n][r];
        }
      }
    }
  }
}

extern "C" void kernel_launch(void* const* d_in, const int* in_sizes, int n_in,
                              void* d_out, int out_size, void* d_ws, size_t ws_size,
                              hipStream_t stream) {
  const float* x_m = (const float*)d_in[0];
  const float* x_d = (const float*)d_in[1];
  const int* em = (const int*)d_in[2];
  const int* ed = (const int*)d_in[3];
  const float* Wx = (const float*)d_in[4];
  const float* axs = (const float*)d_in[5];
  const float* axd = (const float*)d_in[6];
  const float* bx = (const float*)d_in[7];
  const float* Wy = (const float*)d_in[8];
  const float* ays = (const float*)d_in[9];
  const float* ayd = (const float*)d_in[10];
  const float* by = (const float*)d_in[11];
  const float* wcx = (const float*)d_in[12];
  const float* bcx = (const float*)d_in[13];
  const float* wcy = (const float*)d_in[14];
  const float* bcy = (const float*)d_in[15];
  float* out = (float*)d_out;

  char* w = (char*)d_ws;
  size_t off = 0;
  auto alloc = [&](size_t bytes) -> void* {
    void* p = w + off;
    off += (bytes + 511) & ~(size_t)511;
    return p;
  };
  Br b[2];
  for (int i = 0; i < 2; ++i) {
    b[i].cnt = (int*)alloc(NN * 4);
    b[i].rowptr = (int*)alloc((NN + 1) * 4);
    b[i].srcidx = (int*)alloc((size_t)TT * 4);
    b[i].alpha = (float*)alloc((size_t)TT * 4);
    b[i].hp = (float*)alloc((size_t)NN * FF * 4);
    b[i].s1 = (float*)alloc(NN * 4);
    b[i].s2 = (float*)alloc(NN * 4);
    b[i].H = (float*)alloc((size_t)3 * NN * FF * 4);
    b[i].xb = (uint16_t*)alloc((size_t)NN * FF * 2);
    b[i].wct = (float*)alloc((size_t)384 * EMD_ * 4);
  }

  // CSR build (shared by all layers)
  k_init<<<dim3(40, 2), 256, 0, stream>>>(b[0], b[1]);
  k_hist<<<dim3(1250, 2), 256, 0, stream>>>(b[0], b[1], em, ed);
  k_scan<<<dim3(2), 1024, 0, stream>>>(b[0], b[1]);
  k_scatter<<<dim3(1290, 2), 256, 0, stream>>>(b[0], b[1], em, ed);
  k_twc<<<dim3(192, 2), 256, 0, stream>>>(b[0], b[1], wcx, wcy);

  for (int l = 0; l < 3; ++l) {
    const float* in0 = (l == 0) ? x_m : b[0].H + (size_t)(l - 1) * NN * FF;
    const float* in1 = (l == 0) ? x_d : b[1].H + (size_t)(l - 1) * NN * FF;
    k_ngemm<<<dim3(157, 2, 2), 256, 0, stream>>>(b[0], b[1], in0, in1,
                                                 Wx + (size_t)l * FF * FF, Wy + (size_t)l * FF * FF);
    k_scores<<<dim3(2500, 2), 256, 0, stream>>>(b[0], b[1], axs + l * FF, ays + l * FF,
                                                axd + l * FF, ayd + l * FF);
    k_softmax<<<dim3(2500, 2), 256, 0, stream>>>(b[0], b[1]);
    k_agg<<<dim3(10000, 2), 128, 0, stream>>>(b[0], b[1], bx + l * FF, by + l * FF, l);
  }

  k_conv<<<dim3(157, 2, 2), 256, 0, stream>>>(b[0], b[1], bcx, bcy);
  k_final<<<dim3(79, 79), 256, 0, stream>>>(b[0].xb, b[1].xb, out);
}